// Round 4
// baseline (175.535 us; speedup 1.0000x reference)
//
#include <hip/hip_runtime.h>
#include <math.h>

// Whiten: per-(b,c) mean/std over 224x224 fp32 slices. B*C = 2048 slices.
// Memory floor: 411 MB read + 411 MB write @ ~6.3 TB/s ~= 131 us.
//
// R4 = R3 with the nontemporal-store type fixed (clang ext_vector, not
// HIP_vector_type). Structure: two-pass streaming, one 1024-thread block per
// slice:
//   pass 1: stream-read slice, accumulate sum/sumsq  (no register staging)
//   reduce: wave butterfly + LDS cross-wave
//   pass 2: re-read slice (Infinity-Cache-hot), normalize, nontemporal store
// __launch_bounds__(1024,8) caps VGPR at 64 => 2 blocks/CU co-resident =>
// in-flight read set = 512 x 200 KB ~= 100 MB < 256 MB L3. Nontemporal
// stores keep the write stream from evicting those lines. Co-resident blocks
// at different phases cover each other's reduce/retire bubbles.

namespace {
constexpr int kHW      = 224 * 224;                 // 50176
constexpr int kHW4     = kHW / 4;                   // 12544 float4 / slice
constexpr int kThreads = 1024;
constexpr int kIt      = kHW4 / kThreads;           // 12
constexpr int kExtra   = kHW4 - kIt * kThreads;     // 256 tail float4
constexpr int kSlices  = 64 * 32;                   // 2048
constexpr int kWaves   = kThreads / 64;             // 16
constexpr float kMinDev = 1.0f / 224.0f;            // 1/sqrt(H*W)

typedef float vfloat4 __attribute__((ext_vector_type(4)));  // clang vector:
// accepted by __builtin_nontemporal_store, same 16B layout as float4.
}

__global__ __launch_bounds__(kThreads, 8)   // <=64 VGPR -> 2 blocks/CU
void whiten_twopass(const float* __restrict__ x, float* __restrict__ y) {
    __shared__ float wred_s[kWaves];
    __shared__ float wred_q[kWaves];
    __shared__ float stats[2];

    const int tid  = threadIdx.x;
    const int wid  = tid >> 6;
    const int lane = tid & 63;
    const bool extra = (tid < kExtra);
    const size_t base = (size_t)blockIdx.x * kHW4;
    const vfloat4* __restrict__ xs = reinterpret_cast<const vfloat4*>(x) + base;
    vfloat4* __restrict__ ys       = reinterpret_cast<vfloat4*>(y) + base;

    // ---- pass 1: stream + accumulate ----
    float sum = 0.f, ssq = 0.f;
#pragma unroll
    for (int i = 0; i < kIt; ++i) {
        const vfloat4 v = xs[tid + i * kThreads];
        sum += v.x + v.y + v.z + v.w;
        ssq = fmaf(v.x, v.x, ssq);
        ssq = fmaf(v.y, v.y, ssq);
        ssq = fmaf(v.z, v.z, ssq);
        ssq = fmaf(v.w, v.w, ssq);
    }
    if (extra) {
        const vfloat4 v = xs[kIt * kThreads + tid];
        sum += v.x + v.y + v.z + v.w;
        ssq = fmaf(v.x, v.x, ssq);
        ssq = fmaf(v.y, v.y, ssq);
        ssq = fmaf(v.z, v.z, ssq);
        ssq = fmaf(v.w, v.w, ssq);
    }

    // ---- wave64 butterfly ----
#pragma unroll
    for (int off = 32; off >= 1; off >>= 1) {
        sum += __shfl_down(sum, off, 64);
        ssq += __shfl_down(ssq, off, 64);
    }
    if (lane == 0) { wred_s[wid] = sum; wred_q[wid] = ssq; }
    __syncthreads();
    if (tid == 0) {
        float S = 0.f, SS = 0.f;
#pragma unroll
        for (int i = 0; i < kWaves; ++i) { S += wred_s[i]; SS += wred_q[i]; }
        const float mean = S * (1.0f / kHW);
        float var = (SS - S * mean) * (1.0f / (kHW - 1));
        var = fmaxf(var, 0.f);
        stats[0] = mean;
        stats[1] = 1.0f / fmaxf(sqrtf(var), kMinDev);
    }
    __syncthreads();
    const float mean = stats[0];
    const float rcp  = stats[1];

    // ---- pass 2: re-read (L3-hot), normalize, nontemporal store ----
#pragma unroll
    for (int i = 0; i < kIt; ++i) {
        const vfloat4 v = xs[tid + i * kThreads];
        vfloat4 o;
        o.x = (v.x - mean) * rcp;
        o.y = (v.y - mean) * rcp;
        o.z = (v.z - mean) * rcp;
        o.w = (v.w - mean) * rcp;
        __builtin_nontemporal_store(o, &ys[tid + i * kThreads]);
    }
    if (extra) {
        const vfloat4 v = xs[kIt * kThreads + tid];
        vfloat4 o;
        o.x = (v.x - mean) * rcp;
        o.y = (v.y - mean) * rcp;
        o.z = (v.z - mean) * rcp;
        o.w = (v.w - mean) * rcp;
        __builtin_nontemporal_store(o, &ys[kIt * kThreads + tid]);
    }
}

extern "C" void kernel_launch(void* const* d_in, const int* in_sizes, int n_in,
                              void* d_out, int out_size, void* d_ws, size_t ws_size,
                              hipStream_t stream) {
    (void)in_sizes; (void)n_in; (void)d_ws; (void)ws_size; (void)out_size;
    const float* x = reinterpret_cast<const float*>(d_in[0]);
    float* y = reinterpret_cast<float*>(d_out);
    whiten_twopass<<<kSlices, kThreads, 0, stream>>>(x, y);
}

// Round 5
// 164.850 us; speedup vs baseline: 1.0648x; 1.0648x over previous
//
#include <hip/hip_runtime.h>
#include <math.h>

// Whiten: per-(b,c) mean/std over 224x224 fp32 slices. B*C = 2048 slices.
// Floor: 411 MB read + 411 MB write @ ~6.3 TB/s ~= 131 us.
//
// R5: single-read staging (like R1) but restructured for 2 co-resident
// blocks/CU so their phases interleave and cover each other's reduce/barrier
// bubbles (R1 was 1 block/CU => ~25 us of serial bubble over 8 rounds).
//   - 512-thread blocks, one slice each, grid = 2048.
//   - Per thread 24.5 float4: 15 staged in registers (60 VGPR),
//     9.5 staged in LDS (4864 float4 = 76 KB/block; 2 blocks = 152 KB <= 160).
//   - __launch_bounds__(512,4): 4 waves/SIMD => VGPR cap 128; design uses
//     ~100 => no spill (R2's failure mode was spilling past 128).
//   - LDS staging temps processed in <=5-float4 chunks to bound live regs.
//   - Stats: wave butterfly -> 8-entry LDS -> one __syncthreads -> every
//     thread reduces the 8 entries (broadcast reads, no tid0 serialization).
//   - Staged-data ds_write/ds_read are same-thread and separated by the
//     stats barrier: no extra synchronization needed.

namespace {
constexpr int kHW       = 224 * 224;                   // 50176
constexpr int kHW4      = kHW / 4;                     // 12544 float4 / slice
constexpr int kThreads  = 512;
constexpr int kWaves    = kThreads / 64;               // 8
constexpr int kRegIt    = 15;                          // float4 in registers
constexpr int kLdsBase  = kRegIt * kThreads;           // 7680
constexpr int kLdsCount = kHW4 - kLdsBase;             // 4864 float4 (76 KB)
constexpr int kLdsFull  = kLdsCount / kThreads;        // 9
constexpr int kLdsExtra = kLdsCount - kLdsFull * kThreads;  // 256 (4 waves)
constexpr int kSlices   = 64 * 32;                     // 2048
constexpr float kMinDev = 1.0f / 224.0f;               // 1/sqrt(H*W)

typedef float vfloat4 __attribute__((ext_vector_type(4)));
}

__global__ __launch_bounds__(kThreads, 4)   // 4 waves/SIMD => 2 blocks/CU
void whiten_hybrid(const float* __restrict__ x, float* __restrict__ y) {
    __shared__ vfloat4 buf[kLdsCount];      // 77824 B staged data
    __shared__ float2  wred[kWaves];        // per-wave (sum, sumsq)

    const int tid  = threadIdx.x;
    const int wid  = tid >> 6;
    const int lane = tid & 63;
    const size_t base = (size_t)blockIdx.x * kHW4;
    const vfloat4* __restrict__ xs = reinterpret_cast<const vfloat4*>(x) + base;
    vfloat4* __restrict__ ys       = reinterpret_cast<vfloat4*>(y) + base;

    float sum = 0.f, ssq = 0.f;
    auto acc = [&](const vfloat4& v) {
        sum += v.x + v.y + v.z + v.w;
        ssq = fmaf(v.x, v.x, ssq);
        ssq = fmaf(v.y, v.y, ssq);
        ssq = fmaf(v.z, v.z, ssq);
        ssq = fmaf(v.w, v.w, ssq);
    };

    // ---- issue register-part loads first (biggest MLP batch) ----
    vfloat4 v[kRegIt];
#pragma unroll
    for (int i = 0; i < kRegIt; ++i) v[i] = xs[tid + i * kThreads];

    // ---- LDS part, chunk 1: 5 float4 (bounded live temps) ----
    {
        vfloat4 t[5];
#pragma unroll
        for (int i = 0; i < 5; ++i) t[i] = xs[kLdsBase + i * kThreads + tid];
#pragma unroll
        for (int i = 0; i < 5; ++i) { acc(t[i]); buf[i * kThreads + tid] = t[i]; }
    }
    // ---- LDS part, chunk 2: 4 float4 + 256-thread tail ----
    {
        vfloat4 t[4];
#pragma unroll
        for (int i = 0; i < 4; ++i) t[i] = xs[kLdsBase + (5 + i) * kThreads + tid];
#pragma unroll
        for (int i = 0; i < 4; ++i) { acc(t[i]); buf[(5 + i) * kThreads + tid] = t[i]; }
        if (tid < kLdsExtra) {   // waves 0-3 only: wave-uniform, no divergence
            vfloat4 te = xs[kLdsBase + kLdsFull * kThreads + tid];
            acc(te);
            buf[kLdsFull * kThreads + tid] = te;
        }
    }

    // ---- accumulate register part ----
#pragma unroll
    for (int i = 0; i < kRegIt; ++i) acc(v[i]);

    // ---- wave64 butterfly ----
#pragma unroll
    for (int off = 32; off >= 1; off >>= 1) {
        sum += __shfl_down(sum, off, 64);
        ssq += __shfl_down(ssq, off, 64);
    }
    if (lane == 0) wred[wid] = make_float2(sum, ssq);
    __syncthreads();

    // ---- every thread reduces the 8 wave entries (broadcast reads) ----
    float S = 0.f, SS = 0.f;
#pragma unroll
    for (int i = 0; i < kWaves; ++i) { S += wred[i].x; SS += wred[i].y; }
    const float mean = S * (1.0f / kHW);
    float var = (SS - S * mean) * (1.0f / (kHW - 1));
    var = fmaxf(var, 0.f);
    const float rcp = 1.0f / fmaxf(sqrtf(var), kMinDev);

    // ---- normalize + store register part ----
#pragma unroll
    for (int i = 0; i < kRegIt; ++i) {
        vfloat4 o;
        o.x = (v[i].x - mean) * rcp;
        o.y = (v[i].y - mean) * rcp;
        o.z = (v[i].z - mean) * rcp;
        o.w = (v[i].w - mean) * rcp;
        ys[tid + i * kThreads] = o;
    }
    // ---- normalize + store LDS part ----
#pragma unroll
    for (int i = 0; i < kLdsFull; ++i) {
        const vfloat4 t = buf[i * kThreads + tid];
        vfloat4 o;
        o.x = (t.x - mean) * rcp;
        o.y = (t.y - mean) * rcp;
        o.z = (t.z - mean) * rcp;
        o.w = (t.w - mean) * rcp;
        ys[kLdsBase + i * kThreads + tid] = o;
    }
    if (tid < kLdsExtra) {
        const vfloat4 t = buf[kLdsFull * kThreads + tid];
        vfloat4 o;
        o.x = (t.x - mean) * rcp;
        o.y = (t.y - mean) * rcp;
        o.z = (t.z - mean) * rcp;
        o.w = (t.w - mean) * rcp;
        ys[kLdsBase + kLdsFull * kThreads + tid] = o;
    }
}

extern "C" void kernel_launch(void* const* d_in, const int* in_sizes, int n_in,
                              void* d_out, int out_size, void* d_ws, size_t ws_size,
                              hipStream_t stream) {
    (void)in_sizes; (void)n_in; (void)d_ws; (void)ws_size; (void)out_size;
    const float* x = reinterpret_cast<const float*>(d_in[0]);
    float* y = reinterpret_cast<float*>(d_out);
    whiten_hybrid<<<kSlices, kThreads, 0, stream>>>(x, y);
}